// Round 2
// baseline (103.625 us; speedup 1.0000x reference)
//
#include <hip/hip_runtime.h>

#define B_ROWS   256
#define SPLIT    8                      // segments (blocks) per row
#define NTHREADS 256                    // 4 waves
#define NBLOCKS  (B_ROWS * SPLIT)       // 2048 = 8 blocks/CU, all co-resident

// ws layout: [0, NBLOCKS*5 floats) = partials; u32 ticket at byte offset NBLOCKS*5*4
#define TICKET_OFF (NBLOCKS * 5 * sizeof(float))

// ---------------------------------------------------------------------------
// Fused kernel: per-(row,segment) partial sums of {x, y, xy, x^2, y^2};
// the last block to finish combines all partials and writes the scalar.
// ---------------------------------------------------------------------------
__global__ __launch_bounds__(NTHREADS, 8) void pearson_fused(
    const float* __restrict__ preds,
    const float* __restrict__ labels,
    float* __restrict__ ws,              // [NBLOCKS][5]
    unsigned int* __restrict__ ticket,   // zeroed by memsetAsync each call
    float* __restrict__ out,
    int N)
{
    const int bid = blockIdx.x;
    const int row = bid >> 3;            // / SPLIT
    const int seg = bid & (SPLIT - 1);
    const int tid = threadIdx.x;

    const int n4      = N >> 2;          // float4 per row (N % 4 == 0)
    const int per_seg = n4 / SPLIT;      // exact for N=100000 -> 3125
    const int begin   = seg * per_seg;

    const float4* p4 = reinterpret_cast<const float4*>(preds  + (size_t)row * N);
    const float4* l4 = reinterpret_cast<const float4*>(labels + (size_t)row * N);

    float sx = 0.f, sy = 0.f, sxy = 0.f, sxx = 0.f, syy = 0.f;

    const int full = per_seg / NTHREADS;             // 12
    const int rem  = per_seg - full * NTHREADS;      // 53

    int i = begin + tid;
#pragma unroll 4
    for (int k = 0; k < full; ++k, i += NTHREADS) {
        float4 a = p4[i];
        float4 b = l4[i];
        sx += a.x; sy += b.x; sxy = fmaf(a.x, b.x, sxy); sxx = fmaf(a.x, a.x, sxx); syy = fmaf(b.x, b.x, syy);
        sx += a.y; sy += b.y; sxy = fmaf(a.y, b.y, sxy); sxx = fmaf(a.y, a.y, sxx); syy = fmaf(b.y, b.y, syy);
        sx += a.z; sy += b.z; sxy = fmaf(a.z, b.z, sxy); sxx = fmaf(a.z, a.z, sxx); syy = fmaf(b.z, b.z, syy);
        sx += a.w; sy += b.w; sxy = fmaf(a.w, b.w, sxy); sxx = fmaf(a.w, a.w, sxx); syy = fmaf(b.w, b.w, syy);
    }
    if (tid < rem) {
        float4 a = p4[i];
        float4 b = l4[i];
        sx += a.x; sy += b.x; sxy = fmaf(a.x, b.x, sxy); sxx = fmaf(a.x, a.x, sxx); syy = fmaf(b.x, b.x, syy);
        sx += a.y; sy += b.y; sxy = fmaf(a.y, b.y, sxy); sxx = fmaf(a.y, a.y, sxx); syy = fmaf(b.y, b.y, syy);
        sx += a.z; sy += b.z; sxy = fmaf(a.z, b.z, sxy); sxx = fmaf(a.z, a.z, sxx); syy = fmaf(b.z, b.z, syy);
        sx += a.w; sy += b.w; sxy = fmaf(a.w, b.w, sxy); sxx = fmaf(a.w, a.w, sxx); syy = fmaf(b.w, b.w, syy);
    }

    // wave-64 butterfly reduction
    for (int o = 32; o > 0; o >>= 1) {
        sx  += __shfl_down(sx,  o, 64);
        sy  += __shfl_down(sy,  o, 64);
        sxy += __shfl_down(sxy, o, 64);
        sxx += __shfl_down(sxx, o, 64);
        syy += __shfl_down(syy, o, 64);
    }

    __shared__ float red[4][5];
    __shared__ int   s_last;
    const int wave = tid >> 6;
    const int lane = tid & 63;
    if (lane == 0) {
        red[wave][0] = sx;  red[wave][1] = sy;  red[wave][2] = sxy;
        red[wave][3] = sxx; red[wave][4] = syy;
    }
    __syncthreads();

    if (tid == 0) {
        float* w = ws + (size_t)bid * 5;
        w[0] = red[0][0] + red[1][0] + red[2][0] + red[3][0];
        w[1] = red[0][1] + red[1][1] + red[2][1] + red[3][1];
        w[2] = red[0][2] + red[1][2] + red[2][2] + red[3][2];
        w[3] = red[0][3] + red[1][3] + red[2][3] + red[3][3];
        w[4] = red[0][4] + red[1][4] + red[2][4] + red[3][4];
        __threadfence();                               // release partials (device scope)
        unsigned int old = atomicAdd(ticket, 1u);      // device-scope atomic
        s_last = (old == NBLOCKS - 1) ? 1 : 0;
    }
    __syncthreads();
    if (!s_last) return;

    // ---- last block: combine partials, compute mean(1 - r) ----
    __threadfence();                                   // acquire

    const int t = tid;                                 // row index (NTHREADS == B_ROWS)
    double dsx = 0.0, dsy = 0.0, dsxy = 0.0, dsxx = 0.0, dsyy = 0.0;
#pragma unroll
    for (int s = 0; s < SPLIT; ++s) {
        const float* w = ws + ((size_t)t * SPLIT + s) * 5;
        dsx  += (double)w[0];
        dsy  += (double)w[1];
        dsxy += (double)w[2];
        dsxx += (double)w[3];
        dsyy += (double)w[4];
    }

    const double n   = (double)N;
    const double num = n * dsxy - dsx * dsy;
    const double den = sqrt((n * dsxx - dsx * dsx) * (n * dsyy - dsy * dsy));
    double val = 1.0 - num / den;

    for (int o = 32; o > 0; o >>= 1)
        val += __shfl_down(val, o, 64);

    __shared__ double dred[4];
    if (lane == 0) dred[wave] = val;
    __syncthreads();

    if (tid == 0)
        out[0] = (float)((dred[0] + dred[1] + dred[2] + dred[3]) / (double)B_ROWS);
}

// ---------------------------------------------------------------------------
extern "C" void kernel_launch(void* const* d_in, const int* in_sizes, int n_in,
                              void* d_out, int out_size, void* d_ws, size_t ws_size,
                              hipStream_t stream)
{
    const float* preds  = (const float*)d_in[0];
    const float* labels = (const float*)d_in[1];
    // d_in[2] = subject (scalar int), unused by the math.

    const int N = in_sizes[0] / B_ROWS;   // 100000

    float*        ws     = (float*)d_ws;
    unsigned int* ticket = (unsigned int*)((char*)d_ws + TICKET_OFF);
    float*        out    = (float*)d_out;

    hipMemsetAsync(ticket, 0, sizeof(unsigned int), stream);   // graph-capturable
    pearson_fused<<<NBLOCKS, NTHREADS, 0, stream>>>(preds, labels, ws, ticket, out, N);
}

// Round 3
// 37.824 us; speedup vs baseline: 2.7397x; 2.7397x over previous
//
#include <hip/hip_runtime.h>

#define B_ROWS   256
#define SPLIT    8                      // segments (blocks) per row
#define NTHREADS 256                    // 4 waves
#define NBLOCKS  (B_ROWS * SPLIT)       // 2048 = 8 blocks/CU

// ws layout (SoA): component j in ws[j*NBLOCKS + bid], j in {0..4}
// -> final kernel reads 8 consecutive floats per (row, component): float4-able.

// ---------------------------------------------------------------------------
// Kernel 1: per-(row,segment) partial sums of {x, y, xy, x^2, y^2}.
// Identical streaming loop to the round-1 kernel (proven ~6.2 TB/s).
// ---------------------------------------------------------------------------
__global__ __launch_bounds__(NTHREADS) void pearson_partial(
    const float* __restrict__ preds,
    const float* __restrict__ labels,
    float* __restrict__ ws,   // [5][NBLOCKS]
    int N)
{
    const int bid = blockIdx.x;
    const int row = bid >> 3;            // / SPLIT
    const int seg = bid & (SPLIT - 1);
    const int tid = threadIdx.x;

    const int n4      = N >> 2;          // float4 per row (N % 4 == 0)
    const int per_seg = n4 / SPLIT;      // 3125 (exact)
    const int begin   = seg * per_seg;
    const int end     = begin + per_seg;

    const float4* p4 = reinterpret_cast<const float4*>(preds  + (size_t)row * N);
    const float4* l4 = reinterpret_cast<const float4*>(labels + (size_t)row * N);

    float sx = 0.f, sy = 0.f, sxy = 0.f, sxx = 0.f, syy = 0.f;

    for (int i = begin + tid; i < end; i += NTHREADS) {
        float4 a = p4[i];
        float4 b = l4[i];
        sx += a.x; sy += b.x; sxy = fmaf(a.x, b.x, sxy); sxx = fmaf(a.x, a.x, sxx); syy = fmaf(b.x, b.x, syy);
        sx += a.y; sy += b.y; sxy = fmaf(a.y, b.y, sxy); sxx = fmaf(a.y, a.y, sxx); syy = fmaf(b.y, b.y, syy);
        sx += a.z; sy += b.z; sxy = fmaf(a.z, b.z, sxy); sxx = fmaf(a.z, a.z, sxx); syy = fmaf(b.z, b.z, syy);
        sx += a.w; sy += b.w; sxy = fmaf(a.w, b.w, sxy); sxx = fmaf(a.w, a.w, sxx); syy = fmaf(b.w, b.w, syy);
    }

    // wave-64 butterfly reduction
    for (int o = 32; o > 0; o >>= 1) {
        sx  += __shfl_down(sx,  o, 64);
        sy  += __shfl_down(sy,  o, 64);
        sxy += __shfl_down(sxy, o, 64);
        sxx += __shfl_down(sxx, o, 64);
        syy += __shfl_down(syy, o, 64);
    }

    __shared__ float red[4][5];
    const int wave = tid >> 6;
    const int lane = tid & 63;
    if (lane == 0) {
        red[wave][0] = sx;  red[wave][1] = sy;  red[wave][2] = sxy;
        red[wave][3] = sxx; red[wave][4] = syy;
    }
    __syncthreads();

    if (tid == 0) {
        // SoA writes: one 4B store per component, stride NBLOCKS
        ws[0 * NBLOCKS + bid] = red[0][0] + red[1][0] + red[2][0] + red[3][0];
        ws[1 * NBLOCKS + bid] = red[0][1] + red[1][1] + red[2][1] + red[3][1];
        ws[2 * NBLOCKS + bid] = red[0][2] + red[1][2] + red[2][2] + red[3][2];
        ws[3 * NBLOCKS + bid] = red[0][3] + red[1][3] + red[2][3] + red[3][3];
        ws[4 * NBLOCKS + bid] = red[0][4] + red[1][4] + red[2][4] + red[3][4];
    }
}

// ---------------------------------------------------------------------------
// Kernel 2: combine SPLIT partials per row (double), compute 1 - pearson,
// mean over rows. 1 block x 256 threads (one thread per row).
// SoA layout -> per thread, per component: 2 coalesced float4 loads.
// ---------------------------------------------------------------------------
__global__ __launch_bounds__(NTHREADS) void pearson_final(
    const float* __restrict__ ws,
    float* __restrict__ out,
    int N)
{
    const int t = threadIdx.x;   // row index (NTHREADS == B_ROWS)
    const float4* ws4 = reinterpret_cast<const float4*>(ws);

    // issue all 10 independent float4 loads up front (one latency round-trip)
    float4 v[5][2];
#pragma unroll
    for (int j = 0; j < 5; ++j) {
        v[j][0] = ws4[j * (NBLOCKS / 4) + 2 * t];
        v[j][1] = ws4[j * (NBLOCKS / 4) + 2 * t + 1];
    }

    double acc[5];
#pragma unroll
    for (int j = 0; j < 5; ++j) {
        acc[j] = (double)v[j][0].x + (double)v[j][0].y + (double)v[j][0].z + (double)v[j][0].w
               + (double)v[j][1].x + (double)v[j][1].y + (double)v[j][1].z + (double)v[j][1].w;
    }

    const double n   = (double)N;
    const double num = n * acc[2] - acc[0] * acc[1];
    const double den = sqrt((n * acc[3] - acc[0] * acc[0]) * (n * acc[4] - acc[1] * acc[1]));
    double val = 1.0 - num / den;

    for (int o = 32; o > 0; o >>= 1)
        val += __shfl_down(val, o, 64);

    __shared__ double dred[4];
    const int wave = t >> 6;
    const int lane = t & 63;
    if (lane == 0) dred[wave] = val;
    __syncthreads();

    if (t == 0)
        out[0] = (float)((dred[0] + dred[1] + dred[2] + dred[3]) / (double)B_ROWS);
}

// ---------------------------------------------------------------------------
extern "C" void kernel_launch(void* const* d_in, const int* in_sizes, int n_in,
                              void* d_out, int out_size, void* d_ws, size_t ws_size,
                              hipStream_t stream)
{
    const float* preds  = (const float*)d_in[0];
    const float* labels = (const float*)d_in[1];
    // d_in[2] = subject (scalar int), unused by the math.

    const int N = in_sizes[0] / B_ROWS;   // 100000

    float* ws  = (float*)d_ws;            // 5*NBLOCKS floats = 40 KiB
    float* out = (float*)d_out;

    pearson_partial<<<NBLOCKS, NTHREADS, 0, stream>>>(preds, labels, ws, N);
    pearson_final<<<1, NTHREADS, 0, stream>>>(ws, out, N);
}